// Round 1
// baseline (394.488 us; speedup 1.0000x reference)
//
#include <hip/hip_runtime.h>
#include <math.h>

// Problem constants (DirectImageAlign): B=4, C=16, H=240, W=320
#define B_   4
#define C_   16
#define H_   240
#define W_   320
#define HW_  (H_*W_)
#define NBX  128      // blocks per batch in reduce kernel
#define NACC 27       // 21 (sym 6x6 JtJ) + 6 (rhs)
#define GEOM_W_ 0.01f
#define HUBER_  1.345f
#define LM_EPS_ 1e-6
#define N_ITERS_ 5

__global__ void dia_init_pose(const float* __restrict__ pose_in, float* __restrict__ pose) {
    int i = threadIdx.x;
    if (i < B_*16) pose[i] = pose_in[i];
}

// Bilinear sample of img, d/dx(img), d/dy(img) at (x0+fx1, y0+fy1).
// Central-difference gradients with edge clamping, matching
// _feature_gradient + _grid_sample of the reference for in-bounds coords.
__device__ __forceinline__ void samp12(const float* __restrict__ img,
                                       int x0, int y0, int xm1, int xp2, int ym1, int yp2,
                                       float w00, float w10, float w01, float w11,
                                       float& sv, float& sdx, float& sdy)
{
    const float* r0 = img + y0 * W_;
    const float* r1 = r0 + W_;
    float A0 = r0[xm1], A1 = r0[x0], A2 = r0[x0+1], A3 = r0[xp2];
    float B0 = r1[xm1], B1 = r1[x0], B2 = r1[x0+1], B3 = r1[xp2];
    const float* ru = img + ym1 * W_;
    const float* rd = img + yp2 * W_;
    float U0 = ru[x0], U1 = ru[x0+1];
    float D0 = rd[x0], D1 = rd[x0+1];
    sv  = w00*A1 + w10*A2 + w01*B1 + w11*B2;
    sdx = 0.5f*( w00*(A2-A0) + w10*(A3-A1) + w01*(B2-B0) + w11*(B3-B1) );
    sdy = 0.5f*( w00*(B1-U0) + w10*(B2-U1) + w01*(D0-A1) + w11*(D1-A2) );
}

__global__ __launch_bounds__(256) void dia_reduce(
    const float* __restrict__ pose,
    const float* __restrict__ I0,
    const float* __restrict__ I1,
    const float* __restrict__ intr,
    const float* __restrict__ depth0,
    const float* __restrict__ depth1,
    double* __restrict__ partial)
{
    const int b = blockIdx.y;
    const float fxv = intr[b*4+0], fyv = intr[b*4+1];
    const float cx  = intr[b*4+2], cy  = intr[b*4+3];

    float Rm[9], tv[3];
#pragma unroll
    for (int i = 0; i < 3; ++i) {
#pragma unroll
        for (int j = 0; j < 3; ++j) Rm[i*3+j] = pose[b*16 + i*4 + j];
        tv[i] = pose[b*16 + i*4 + 3];
    }

    const float* d0p = depth0 + b * HW_;
    const float* d1p = depth1 + b * HW_;
    const float* I0b = I0 + (size_t)b * C_ * HW_;
    const float* I1b = I1 + (size_t)b * C_ * HW_;

    double acc[NACC];
#pragma unroll
    for (int i = 0; i < NACC; ++i) acc[i] = 0.0;

    for (int p = blockIdx.x * 256 + threadIdx.x; p < HW_; p += NBX * 256) {
        const int v = p / W_;
        const int u = p - v * W_;

        const float d1 = d1p[p];
        // Back-project pixel of frame-1
        const float X1x = d1 * ((float)u - cx) / fxv;
        const float X1y = d1 * ((float)v - cy) / fyv;
        const float X1z = d1;
        // Transform into frame-0
        const float x = Rm[0]*X1x + Rm[1]*X1y + Rm[2]*X1z + tv[0];
        const float y = Rm[3]*X1x + Rm[4]*X1y + Rm[5]*X1z + tv[1];
        const float z = Rm[6]*X1x + Rm[7]*X1y + Rm[8]*X1z + tv[2];

        const bool vproj = z > 1e-6f;
        const float zs = vproj ? z : 1.0f;
        const float u0 = fxv * x / zs + cx;
        const float v0 = fyv * y / zs + cy;
        const bool inb = (u0 > 0.f) && (u0 < (float)(W_-1)) && (v0 > 0.f) && (v0 < (float)(H_-1));
        const bool valid = inb && vproj && (d0p[p] > 0.f) && (d1 > 0.f);
        if (!valid) continue;

        // Bilinear corner setup (all corners in-bounds when valid)
        const float x0f = floorf(u0), y0f = floorf(v0);
        const int x0 = (int)x0f, y0 = (int)y0f;
        const float fx1 = u0 - x0f, fy1 = v0 - y0f;
        const float w00 = (1.f-fx1)*(1.f-fy1), w10 = fx1*(1.f-fy1);
        const float w01 = (1.f-fx1)*fy1,       w11 = fx1*fy1;
        const int xm1 = max(x0-1, 0), xp2 = min(x0+2, W_-1);
        const int ym1 = max(y0-1, 0), yp2 = min(y0+2, H_-1);

        // Warp Jacobian Jw = Jp(2x3) @ Jt(3x6)
        const float iz = 1.f / zs;
        float Jp[2][3];
        Jp[0][0] = fxv * iz; Jp[0][1] = 0.f;       Jp[0][2] = -fxv * x * iz * iz;
        Jp[1][0] = 0.f;      Jp[1][1] = fyv * iz;  Jp[1][2] = -fyv * y * iz * iz;
        float Jt2[3][6] = {
            {1.f, 0.f, 0.f, 0.f,  z,  -y},
            {0.f, 1.f, 0.f, -z,  0.f,  x},
            {0.f, 0.f, 1.f,  y,  -x,  0.f}
        };
        float Jw[2][6];
#pragma unroll
        for (int i = 0; i < 2; ++i)
#pragma unroll
            for (int j = 0; j < 6; ++j)
                Jw[i][j] = Jp[i][0]*Jt2[0][j] + Jp[i][1]*Jt2[1][j] + Jp[i][2]*Jt2[2][j];

        // Geometric residual
        float D0w, dDx, dDy;
        samp12(d0p, x0, y0, xm1, xp2, ym1, yp2, w00, w10, w01, w11, D0w, dDx, dDy);
        const float rZ = z - D0w;
        float JZ[6];
#pragma unroll
        for (int j = 0; j < 6; ++j) JZ[j] = dDx*Jw[0][j] + dDy*Jw[1][j] - Jt2[2][j];
        const float arz = fabsf(GEOM_W_ * rZ);
        const float wz = (arz <= HUBER_) ? 1.f : HUBER_ / fmaxf(arz, 1e-8f);
        const float wz2 = wz * GEOM_W_ * GEOM_W_;

        // Photometric channels collapse to a 2x2 Gram + 2-vector
        float Ga = 0.f, Gb = 0.f, Gd = 0.f, grx = 0.f, gry = 0.f;
#pragma unroll 4
        for (int c = 0; c < C_; ++c) {
            const float* ip = I0b + c * HW_;
            float Iw, gxc, gyc;
            samp12(ip, x0, y0, xm1, xp2, ym1, yp2, w00, w10, w01, w11, Iw, gxc, gyc);
            const float r = I1b[c * HW_ + p] - Iw;
            const float ar = fabsf(r);
            const float wc = (ar <= HUBER_) ? 1.f : HUBER_ / fmaxf(ar, 1e-8f);
            Ga  += wc * gxc * gxc;
            Gb  += wc * gxc * gyc;
            Gd  += wc * gyc * gyc;
            grx += wc * r * gxc;
            gry += wc * r * gyc;
        }

        // Accumulate per-pixel JtJ (upper triangle) + rhs into f64
        int k = 0;
#pragma unroll
        for (int i = 0; i < 6; ++i) {
#pragma unroll
            for (int j = i; j < 6; ++j) {
                const float vterm = Ga * Jw[0][i] * Jw[0][j]
                                  + Gb * (Jw[0][i] * Jw[1][j] + Jw[1][i] * Jw[0][j])
                                  + Gd * Jw[1][i] * Jw[1][j]
                                  + wz2 * JZ[i] * JZ[j];
                acc[k++] += (double)vterm;
            }
        }
#pragma unroll
        for (int i = 0; i < 6; ++i)
            acc[21 + i] += (double)(grx * Jw[0][i] + gry * Jw[1][i] + wz2 * rZ * JZ[i]);
    }

    // Block reduction: wave shuffle then cross-wave via LDS
    __shared__ double sred[4][NACC];
    const int lane = threadIdx.x & 63;
    const int wid  = threadIdx.x >> 6;
#pragma unroll
    for (int i = 0; i < NACC; ++i) {
        double vsum = acc[i];
#pragma unroll
        for (int off = 32; off > 0; off >>= 1) vsum += __shfl_down(vsum, off, 64);
        if (lane == 0) sred[wid][i] = vsum;
    }
    __syncthreads();
    if (threadIdx.x < NACC) {
        double s = sred[0][threadIdx.x] + sred[1][threadIdx.x]
                 + sred[2][threadIdx.x] + sred[3][threadIdx.x];
        partial[((size_t)blockIdx.x * B_ + b) * NACC + threadIdx.x] = s;
    }
}

__global__ __launch_bounds__(128) void dia_solve(const double* __restrict__ partial,
                                                 float* __restrict__ pose)
{
    __shared__ double S[B_][NACC];
    const int t = threadIdx.x;
    if (t < B_ * NACC) {
        const int b = t / NACC, i = t - b * NACC;
        double s = 0.0;
        for (int k = 0; k < NBX; ++k) s += partial[((size_t)k * B_ + b) * NACC + i];
        S[b][i] = s;
    }
    __syncthreads();
    if (t < B_) {
        // Build H = JtJ + eps*I and rhs
        double Hm[6][7];
        {
            double JtJ[6][6];
            int k = 0;
            for (int i = 0; i < 6; ++i)
                for (int j = i; j < 6; ++j) { JtJ[i][j] = S[t][k]; JtJ[j][i] = S[t][k]; ++k; }
            for (int i = 0; i < 6; ++i) {
                for (int j = 0; j < 6; ++j) Hm[i][j] = JtJ[i][j] + (i == j ? LM_EPS_ : 0.0);
                Hm[i][6] = S[t][21 + i];
            }
        }
        // Gaussian elimination with partial pivoting
        double xi[6];
        for (int col = 0; col < 6; ++col) {
            int piv = col; double mx = fabs(Hm[col][col]);
            for (int r2 = col+1; r2 < 6; ++r2) { double a = fabs(Hm[r2][col]); if (a > mx) { mx = a; piv = r2; } }
            if (piv != col)
                for (int j2 = col; j2 < 7; ++j2) { double tmp = Hm[col][j2]; Hm[col][j2] = Hm[piv][j2]; Hm[piv][j2] = tmp; }
            const double inv = 1.0 / Hm[col][col];
            for (int r2 = col+1; r2 < 6; ++r2) {
                const double f = Hm[r2][col] * inv;
                for (int j2 = col; j2 < 7; ++j2) Hm[r2][j2] -= f * Hm[col][j2];
            }
        }
        for (int r2 = 5; r2 >= 0; --r2) {
            double s = Hm[r2][6];
            for (int j2 = r2+1; j2 < 6; ++j2) s -= Hm[r2][j2] * xi[j2];
            xi[r2] = s / Hm[r2][r2];
        }

        // se3_exp(xi) in double
        const double vx = xi[0], vy = xi[1], vz = xi[2];
        const double wx = xi[3], wy = xi[4], wz = xi[5];
        const double t2 = wx*wx + wy*wy + wz*wz;
        double A, Bc, Cc;
        if (t2 < 1e-8) {
            A  = 1.0 - t2 / 6.0;
            Bc = 0.5 - t2 / 24.0;
            Cc = 1.0/6.0 - t2 / 120.0;
        } else {
            const double th = sqrt(t2);
            const double sth = sin(th), cth = cos(th);
            A  = sth / th;
            Bc = (1.0 - cth) / t2;
            Cc = (th - sth) / (t2 * th);
        }
        const double Wm[9]  = { 0.0, -wz,  wy,
                                wz,  0.0, -wx,
                               -wy,  wx,  0.0 };
        double W2[9];
        for (int i = 0; i < 3; ++i)
            for (int j = 0; j < 3; ++j) {
                double s = 0.0;
                for (int k = 0; k < 3; ++k) s += Wm[i*3+k] * Wm[k*3+j];
                W2[i*3+j] = s;
            }
        double Rm[9], Vm[9];
        for (int i = 0; i < 9; ++i) {
            const double id = (i % 4 == 0) ? 1.0 : 0.0;  // i in {0,4,8} -> diagonal
            Rm[i] = id + A  * Wm[i] + Bc * W2[i];
            Vm[i] = id + Bc * Wm[i] + Cc * W2[i];
        }
        const double tx = Vm[0]*vx + Vm[1]*vy + Vm[2]*vz;
        const double ty = Vm[3]*vx + Vm[4]*vy + Vm[5]*vz;
        const double tz = Vm[6]*vx + Vm[7]*vy + Vm[8]*vz;

        // pose <- E @ pose   (E = [R t; 0 1])
        float* P = pose + t * 16;
        double Pm[16];
        for (int i = 0; i < 16; ++i) Pm[i] = (double)P[i];
        double E[16] = { Rm[0], Rm[1], Rm[2], tx,
                         Rm[3], Rm[4], Rm[5], ty,
                         Rm[6], Rm[7], Rm[8], tz,
                         0.0,   0.0,   0.0,   1.0 };
        double out[16];
        for (int i = 0; i < 4; ++i)
            for (int j = 0; j < 4; ++j) {
                double s = 0.0;
                for (int k = 0; k < 4; ++k) s += E[i*4+k] * Pm[k*4+j];
                out[i*4+j] = s;
            }
        for (int i = 0; i < 16; ++i) P[i] = (float)out[i];
    }
}

extern "C" void kernel_launch(void* const* d_in, const int* in_sizes, int n_in,
                              void* d_out, int out_size, void* d_ws, size_t ws_size,
                              hipStream_t stream) {
    const float* pose_in = (const float*)d_in[0];
    const float* I0      = (const float*)d_in[1];
    const float* I1      = (const float*)d_in[2];
    // d_in[3] = invD0, d_in[4] = invD1 : unused by the forward pass
    const float* intr    = (const float*)d_in[5];
    const float* depth0  = (const float*)d_in[6];
    const float* depth1  = (const float*)d_in[7];

    float*  pose    = (float*)d_out;   // working pose lives in d_out
    double* partial = (double*)d_ws;   // NBX*B_*NACC doubles (~110 KB)

    hipLaunchKernelGGL(dia_init_pose, dim3(1), dim3(64), 0, stream, pose_in, pose);
    for (int it = 0; it < N_ITERS_; ++it) {
        hipLaunchKernelGGL(dia_reduce, dim3(NBX, B_), dim3(256), 0, stream,
                           pose, I0, I1, intr, depth0, depth1, partial);
        hipLaunchKernelGGL(dia_solve, dim3(1), dim3(128), 0, stream, partial, pose);
    }
}